// Round 2
// 199.802 us; speedup vs baseline: 1.0563x; 1.0563x over previous
//
#include <hip/hip_runtime.h>
#include <math.h>

#define BB 2
#define TT 2048
#define DD 1024
#define NH 16
#define NKV 4
#define HD 64
#define EPSF 1.1920929e-07f
// T=2048 > TSL=1024 -> nb = 10000 * 2^(64/62); log2(nb) = log2(1e4) + 64/62
#define LOG2_NB 14.319970444065578
// 0.125 (1/sqrt(64)) * log2(e): folded into q so softmax runs in exp2 domain
#define SCALE_LOG2E 0.18033688011112042f
// fixed softmax max (exp2 units): |q.k| <= 8*8*1.5*0.125*log2e = 17.31 < 17.5
#define FIXMAX 17.5f

typedef __attribute__((ext_vector_type(8))) short bf16x8;
typedef __attribute__((ext_vector_type(4))) float f32x4;

__device__ inline short f2bf(float f) {
    unsigned u = __builtin_bit_cast(unsigned, f);
    unsigned r = (u + 0x7fffu + ((u >> 16) & 1u)) >> 16;
    return (short)r;
}
__device__ inline float bf2f(short s) {
    unsigned u = ((unsigned)(unsigned short)s) << 16;
    return __builtin_bit_cast(float, u);
}
// packed f32x2 -> bf16x2 (hardware RNE rounding, 1 VALU op)
__device__ inline unsigned cvt_pk_bf16(float a, float b) {
    unsigned r;
    asm("v_cvt_pk_bf16_f32 %0, %1, %2" : "=v"(r) : "v"(a), "v"(b));
    return r;
}

// ---------------- fused fp32 -> bf16 conversion for all 5 tensors ----------------
__global__ __launch_bounds__(256) void conv_all(
    const float* __restrict__ x, const float* __restrict__ qw,
    const float* __restrict__ kw, const float* __restrict__ vw,
    const float* __restrict__ ow,
    short* __restrict__ x16, short* __restrict__ wb16, short* __restrict__ ow16)
{
    int i = blockIdx.x * 256 + threadIdx.x;   // float4 index, total 1703936
    const float* src; short* dst; int j;
    if (i < 1048576)      { src = x;  dst = x16;            j = i; }
    else if (i < 1310720) { src = qw; dst = wb16;           j = i - 1048576; }
    else if (i < 1376256) { src = kw; dst = wb16 + 1048576; j = i - 1310720; }
    else if (i < 1441792) { src = vw; dst = wb16 + 1310720; j = i - 1376256; }
    else                  { src = ow; dst = ow16;           j = i - 1441792; }
    float4 v = ((const float4*)src)[j];
    short4 o;
    o.x = f2bf(v.x); o.y = f2bf(v.y); o.z = f2bf(v.z); o.w = f2bf(v.w);
    ((short4*)dst)[j] = o;
}

// ---------------- shared staging macro for 128x128 bf16 GEMM tiles ----------------
#define GSTAGE(buf, k0, Abase, Bbase)                                                   \
{                                                                                       \
    _Pragma("unroll")                                                                   \
    for (int i_ = 0; i_ < 2; i_++) {                                                    \
        int off = w*2048 + i_*1024;           /* byte offset, wave-uniform */           \
        int g = (off >> 4) + lane;            /* 16B chunk idx */                       \
        int row = g >> 2, c = g & 3;                                                    \
        int cg = c ^ (row & 3);               /* XOR swizzle */                         \
        const short* ga = (Abase) + (size_t)(m0 + row)*1024 + (k0) + cg*8;              \
        __builtin_amdgcn_global_load_lds(                                               \
            (const __attribute__((address_space(1))) void*)ga,                          \
            (__attribute__((address_space(3))) void*)((char*)&As[buf][0] + off), 16, 0, 0); \
        const short* gb = (Bbase) + (size_t)(n0 + row)*1024 + (k0) + cg*8;              \
        __builtin_amdgcn_global_load_lds(                                               \
            (const __attribute__((address_space(1))) void*)gb,                          \
            (__attribute__((address_space(3))) void*)((char*)&Bs[buf][0] + off), 16, 0, 0); \
    }                                                                                   \
}

#define GEMM_MAIN_LOOP(kbeg, kend, Abase, Bbase)                                        \
    GSTAGE(0, (kbeg), (Abase), (Bbase));                                                \
    __syncthreads();                                                                    \
    for (int k0 = (kbeg); k0 < (kend); k0 += 32) {                                      \
        int cur = ((k0 - (kbeg)) >> 5) & 1;                                             \
        bf16x8 af[4], bfr[4];                                                           \
        _Pragma("unroll")                                                               \
        for (int tm = 0; tm < 4; tm++) {                                                \
            int row = wy*64 + tm*16 + lc;                                               \
            af[tm] = *(const bf16x8*)(&As[cur][0] + row*32 + ((quad*8) ^ ((row&3)*8))); \
        }                                                                               \
        _Pragma("unroll")                                                               \
        for (int tn = 0; tn < 4; tn++) {                                                \
            int row = wx*64 + tn*16 + lc;                                               \
            bfr[tn] = *(const bf16x8*)(&Bs[cur][0] + row*32 + ((quad*8) ^ ((row&3)*8))); \
        }                                                                               \
        if (k0 + 32 < (kend)) GSTAGE(cur ^ 1, k0 + 32, (Abase), (Bbase));               \
        _Pragma("unroll")                                                               \
        for (int tm = 0; tm < 4; tm++)                                                  \
            _Pragma("unroll")                                                           \
            for (int tn = 0; tn < 4; tn++)                                              \
                acc[tm][tn] = __builtin_amdgcn_mfma_f32_16x16x32_bf16(af[tm], bfr[tn], acc[tm][tn], 0, 0, 0); \
        __syncthreads();                                                                \
    }

// ---------------- QKV GEMM with FUSED epilogue ----------------
// C = x16 * W^T (K=1024, no split-K). Each wave's 64 output cols == one head.
// q/k: RMSNorm + RoPE + gain*scale in-register -> bf16 qbh/kbh
// v:   +ve -> rawv (f32), lambda-mix with v0 -> bf16 vb
__global__ __launch_bounds__(256, 3) void gemm_qkv_fused(
    const short* __restrict__ A, const short* __restrict__ Bmat,
    const float* __restrict__ ve, const float* __restrict__ v0,
    const float* __restrict__ q_gain, const float* __restrict__ vr_lambda,
    short* __restrict__ qbh, short* __restrict__ kbh, short* __restrict__ vb,
    float* __restrict__ rawv)
{
    __shared__ short As[2][128*32];
    __shared__ short Bs[2][128*32];
    int tid = threadIdx.x;
    int w = tid >> 6, lane = tid & 63;
    int quad = lane >> 4, lc = lane & 15;
    int wy = w >> 1, wx = w & 1;
    int m0 = blockIdx.y * 128, n0 = blockIdx.x * 128;

    f32x4 acc[4][4];
    #pragma unroll
    for (int i = 0; i < 4; i++)
        #pragma unroll
        for (int j = 0; j < 4; j++) acc[i][j] = (f32x4){0.f,0.f,0.f,0.f};

    GEMM_MAIN_LOOP(0, 1024, A, Bmat);

    // ---- fused epilogue ----
    int hc = n0 + wx*64;                 // wave-uniform head column base
    if (hc < 1280) {
        // ---- q or k: RMSNorm over the head + RoPE (partner = tn^2, same lane) ----
        bool isq = (hc < 1024);
        int h = isq ? (hc >> 6) : ((hc - 1024) >> 6);
        float gsc = isq ? (q_gain[h] * SCALE_LOG2E) : 1.0f;
        short* dst = isq ? qbh : kbh;
        int nhh = isq ? 16 : 4;
        // per-lane inverse freqs: dr = (tn&1)*16 + lc
        float inv0 = (float)exp2((double)lc * (-LOG2_NB / 32.0));
        float inv1 = (float)exp2((double)(lc + 16) * (-LOG2_NB / 32.0));
        #pragma unroll
        for (int tm = 0; tm < 4; tm++) {
            #pragma unroll
            for (int r = 0; r < 4; r++) {
                int m = m0 + wy*64 + tm*16 + quad*4 + r;
                int b = m >> 11, t = m & (TT - 1);
                float a0 = acc[tm][0][r], a1 = acc[tm][1][r];
                float a2 = acc[tm][2][r], a3 = acc[tm][3][r];
                float ss = a0*a0 + a1*a1 + a2*a2 + a3*a3;
                ss += __shfl_xor(ss, 1);
                ss += __shfl_xor(ss, 2);
                ss += __shfl_xor(ss, 4);
                ss += __shfl_xor(ss, 8);     // 16-lane quad holds one row
                float rn = rsqrtf(ss * (1.0f/64.0f) + EPSF);
                a0 *= rn; a1 *= rn; a2 *= rn; a3 *= rn;
                float sn0, cs0, sn1, cs1;
                sincosf((float)t * inv0, &sn0, &cs0);
                sincosf((float)t * inv1, &sn1, &cs1);
                float o0 = a0*cs0 + a2*sn0;      // d in [0,16)
                float o1 = a1*cs1 + a3*sn1;      // d in [16,32)
                float o2 = a2*cs0 - a0*sn0;      // d in [32,48)
                float o3 = a3*cs1 - a1*sn1;      // d in [48,64)
                size_t base = (((size_t)(b*nhh + h))*2048 + t)*64 + lc;
                dst[base +  0] = f2bf(o0 * gsc);
                dst[base + 16] = f2bf(o1 * gsc);
                dst[base + 32] = f2bf(o2 * gsc);
                dst[base + 48] = f2bf(o3 * gsc);
            }
        }
    } else {
        // ---- v: +ve -> rawv ; lambda-mix -> vb ----
        int vh = (hc - 1280) >> 6;
        float l0 = vr_lambda[0], l1 = vr_lambda[1];
        #pragma unroll
        for (int tm = 0; tm < 4; tm++) {
            #pragma unroll
            for (int r = 0; r < 4; r++) {
                int m = m0 + wy*64 + tm*16 + quad*4 + r;
                size_t off = (size_t)m*256 + vh*64 + lc;
                #pragma unroll
                for (int tn = 0; tn < 4; tn++) {
                    float val = acc[tm][tn][r] + ve[off + tn*16];
                    rawv[off + tn*16] = val;
                    vb[off + tn*16] = f2bf(l0 * v0[off + tn*16] + l1 * val);
                }
            }
        }
    }
}

// ---------------- generic bf16 MFMA GEMM: C = A * B^T (out projection) ----------------
__global__ __launch_bounds__(256, 4) void gemm_mfma(
    const short* __restrict__ A, const short* __restrict__ Bmat,
    float* __restrict__ C, int ldc, int klen)
{
    __shared__ short As[2][128*32];
    __shared__ short Bs[2][128*32];
    int tid = threadIdx.x;
    int w = tid >> 6, lane = tid & 63;
    int quad = lane >> 4, lc = lane & 15;
    int wy = w >> 1, wx = w & 1;
    int m0 = blockIdx.y * 128, n0 = blockIdx.x * 128;

    f32x4 acc[4][4];
    #pragma unroll
    for (int i = 0; i < 4; i++)
        #pragma unroll
        for (int j = 0; j < 4; j++) acc[i][j] = (f32x4){0.f,0.f,0.f,0.f};

    GEMM_MAIN_LOOP(0, klen, A, Bmat);

    #pragma unroll
    for (int tm = 0; tm < 4; tm++)
        #pragma unroll
        for (int r = 0; r < 4; r++) {
            int m = m0 + wy*64 + tm*16 + quad*4 + r;
            #pragma unroll
            for (int tn = 0; tn < 4; tn++) {
                int n = n0 + wx*64 + tn*16 + lc;
                C[(size_t)m*ldc + n] = acc[tm][tn][r];
            }
        }
}

// ---------------- V transpose: vb [b][t][kvh][d] -> vtb [b*4+kvh][d][t] ----------------
__global__ __launch_bounds__(256) void transpose_v(
    const short* __restrict__ vb, short* __restrict__ vtb)
{
    __shared__ short tile[64][72];
    int bk = blockIdx.x;           // b*4+kvh
    int tt = blockIdx.y;           // t tile (64)
    int b = bk >> 2, kvh = bk & 3;
    int tid = threadIdx.x;
    int t4 = tid >> 4;             // 0..15
    int d4 = (tid & 15) * 4;       // 0..60
    #pragma unroll
    for (int i = 0; i < 4; i++) {
        int t = t4 + i*16;
        const short* src = vb + (((size_t)(b*2048 + tt*64 + t)*4 + kvh)*64 + d4);
        *(short4*)&tile[t][d4] = *(const short4*)src;
    }
    __syncthreads();
    #pragma unroll
    for (int i = 0; i < 4; i++) {
        int d = t4 + i*16;
        int t0 = d4;
        short4 o;
        o.x = tile[t0+0][d]; o.y = tile[t0+1][d];
        o.z = tile[t0+2][d]; o.w = tile[t0+3][d];
        *(short4*)&vtb[((size_t)(bk*64 + d))*2048 + tt*64 + t0] = o;
    }
}

// ---------------- gate: sigmoid(x @ gate_w.T + gate_b), x from bf16 ----------------
__global__ __launch_bounds__(256) void gate_kernel(
    const short* __restrict__ x16, const float* __restrict__ gw,
    const float* __restrict__ gb, float* __restrict__ gate)
{
    __shared__ float xs[1024];
    int row = blockIdx.x;
    int tid = threadIdx.x;
    short4 sv = *(const short4*)&x16[(size_t)row*1024 + tid*4];
    xs[tid*4+0] = bf2f(sv.x); xs[tid*4+1] = bf2f(sv.y);
    xs[tid*4+2] = bf2f(sv.z); xs[tid*4+3] = bf2f(sv.w);
    __syncthreads();
    int wave = tid >> 6, lane = tid & 63;
    for (int h = wave; h < 16; h += 4) {
        const float* w = gw + (size_t)h * 1024;
        float s = 0.f;
        #pragma unroll
        for (int i = 0; i < 16; i++) s += xs[lane + 64*i] * w[lane + 64*i];
        #pragma unroll
        for (int off = 32; off; off >>= 1) s += __shfl_xor(s, off);
        if (lane == 0) gate[(size_t)row*16 + h] = 1.0f / (1.0f + __expf(-(s + gb[h])));
    }
}

// ---------------- MFMA flash attention v4: raw v_exp, packed bf16 cvt, l via ones-MFMA ----------------
__global__ __launch_bounds__(256, 4) void flash_mfma(
    const short* __restrict__ qbh, const short* __restrict__ kbh,
    const short* __restrict__ vtb, const float* __restrict__ gate,
    short* __restrict__ y16)
{
    __shared__ short Ks[2][64*64];
    __shared__ short Vt[2][64*64];
    __shared__ short Ps[4][16*64];   // per wave: row q=lc (16), 64 keys; 8B-chunk XOR swizzle

    int bh = blockIdx.x;             // b*16 + h
    int b = bh >> 4, h = bh & 15, kvh = h >> 2;
    int qt = 31 - blockIdx.y;        // long blocks launch first
    int tid = threadIdx.x;
    int w = tid >> 6, lane = tid & 63;
    int quad = lane >> 4, lc = lane & 15;

    const short* qbase = qbh + (((size_t)bh)*2048 + qt*64 + w*16 + lc)*64;
    bf16x8 qf0 = *(const bf16x8*)(qbase + quad*8);
    bf16x8 qf1 = *(const bf16x8*)(qbase + 32 + quad*8);

    f32x4 o[4];
    #pragma unroll
    for (int i = 0; i < 4; i++) o[i] = (f32x4){0.f,0.f,0.f,0.f};
    f32x4 l4 = (f32x4){0.f,0.f,0.f,0.f};      // l in C-layout via P x ones MFMA
    const bf16x8 ones = {(short)0x3F80,(short)0x3F80,(short)0x3F80,(short)0x3F80,
                         (short)0x3F80,(short)0x3F80,(short)0x3F80,(short)0x3F80};

    const size_t kbase = ((size_t)(b*4 + kvh))*2048*64;   // K [t][d]
    const size_t vbase = ((size_t)(b*4 + kvh))*64*2048;   // V^T [d][t]

    #define STAGE(buf, kt)                                                              \
    {                                                                                   \
        _Pragma("unroll")                                                               \
        for (int i = 0; i < 2; i++) {                                                   \
            int off = w*2048 + i*1024;                                                  \
            int g = (off >> 4) + lane;                                                  \
            int row = g >> 3, c = g & 7;                                                \
            int cg = c ^ (row & 7);                                                     \
            const short* gk = kbh + kbase + (size_t)((kt)*64 + row)*64 + cg*8;          \
            __builtin_amdgcn_global_load_lds(                                           \
                (const __attribute__((address_space(1))) void*)gk,                      \
                (__attribute__((address_space(3))) void*)((char*)Ks[buf] + off), 16, 0, 0); \
            const short* gv = vtb + vbase + (size_t)row*2048 + (kt)*64 + cg*8;          \
            __builtin_amdgcn_global_load_lds(                                           \
                (const __attribute__((address_space(1))) void*)gv,                      \
                (__attribute__((address_space(3))) void*)((char*)Vt[buf] + off), 16, 0, 0); \
        }                                                                               \
    }

    STAGE(0, 0);
    __syncthreads();

    short* ps = Ps[w];

    for (int kt = 0; kt <= qt; kt++) {
        int cur = kt & 1;
        bool diag = (kt == qt);

        // 1. preload ALL K/V fragments for this tile (no LDS reads after DMA issue)
        bf16x8 kf0[4], kf1[4], vf0[4], vf1[4];
        #pragma unroll
        for (int kn = 0; kn < 4; kn++) {
            int row = kn*16 + lc;
            int sw = (row & 7) * 8;
            const short* kr = Ks[cur] + row*64;
            kf0[kn] = *(const bf16x8*)(kr + ((quad*8) ^ sw));
            kf1[kn] = *(const bf16x8*)(kr + ((quad*8 + 32) ^ sw));
            const short* vr = Vt[cur] + row*64;
            vf0[kn] = *(const bf16x8*)(vr + ((quad*8) ^ sw));
            vf1[kn] = *(const bf16x8*)(vr + ((quad*8 + 32) ^ sw));
        }
        // 2. prefetch next K/V tile
        if (kt < qt) STAGE(cur ^ 1, kt + 1);

        // 3. S^T = K Q^T : lane holds cols q=lc, rows key = kn*16 + quad*4 + r
        f32x4 s4[4];
        #pragma unroll
        for (int kn = 0; kn < 4; kn++) {
            f32x4 acc = (f32x4){0.f,0.f,0.f,0.f};
            acc = __builtin_amdgcn_mfma_f32_16x16x32_bf16(kf0[kn], qf0, acc, 0, 0, 0);
            acc = __builtin_amdgcn_mfma_f32_16x16x32_bf16(kf1[kn], qf1, acc, 0, 0, 0);
            s4[kn] = acc;
        }

        // 4. p = exp2(s - FIXMAX) (raw v_exp_f32), causal mask, packed cvt, b64 P store
        #pragma unroll
        for (int kn = 0; kn < 4; kn++) {
            float p0 = __builtin_amdgcn_exp2f(s4[kn][0] - FIXMAX);
            float p1 = __builtin_amdgcn_exp2f(s4[kn][1] - FIXMAX);
            float p2 = __builtin_amdgcn_exp2f(s4[kn][2] - FIXMAX);
            float p3 = __builtin_amdgcn_exp2f(s4[kn][3] - FIXMAX);
            if (diag) {
                int keyb = kn*16 + quad*4, qv = w*16 + lc;
                if (keyb + 0 > qv) p0 = 0.f;
                if (keyb + 1 > qv) p1 = 0.f;
                if (keyb + 2 > qv) p2 = 0.f;
                if (keyb + 3 > qv) p3 = 0.f;
            }
            int c = kn*4 + quad;
            int cs = c ^ ((lc & 7) << 1);
            int2 pk;
            pk.x = (int)cvt_pk_bf16(p0, p1);
            pk.y = (int)cvt_pk_bf16(p2, p3);
            *(int2*)(ps + lc*64 + cs*4) = pk;
        }
        __asm__ volatile("s_waitcnt lgkmcnt(0)" ::: "memory");
        // P A-frags: row q=lc, keys kh*32 + quad*8 + (0..7)
        int u0 = (0*4 + quad) ^ (lc & 7);
        int u1 = (1*4 + quad) ^ (lc & 7);
        bf16x8 pf0 = *(const bf16x8*)(ps + lc*64 + u0*8);
        bf16x8 pf1 = *(const bf16x8*)(ps + lc*64 + u1*8);

        // 5. O += P V ; l4 += P x ones (l lands in C-layout rows quad*4+r)
        #pragma unroll
        for (int dn = 0; dn < 4; dn++) {
            o[dn] = __builtin_amdgcn_mfma_f32_16x16x32_bf16(pf0, vf0[dn], o[dn], 0, 0, 0);
            o[dn] = __builtin_amdgcn_mfma_f32_16x16x32_bf16(pf1, vf1[dn], o[dn], 0, 0, 0);
        }
        l4 = __builtin_amdgcn_mfma_f32_16x16x32_bf16(pf0, ones, l4, 0, 0, 0);
        l4 = __builtin_amdgcn_mfma_f32_16x16x32_bf16(pf1, ones, l4, 0, 0, 0);
        __syncthreads();
    }

    #pragma unroll
    for (int r = 0; r < 4; r++) {
        int row = b*2048 + qt*64 + w*16 + quad*4 + r;
        float g = gate[(size_t)row*16 + h] / l4[r];
        #pragma unroll
        for (int dn = 0; dn < 4; dn++)
            y16[(size_t)row*1024 + h*64 + dn*16 + lc] = f2bf(o[dn][r] * g);
    }
}

extern "C" void kernel_launch(void* const* d_in, const int* in_sizes, int n_in,
                              void* d_out, int out_size, void* d_ws, size_t ws_size,
                              hipStream_t stream) {
    (void)in_sizes; (void)n_in; (void)out_size; (void)ws_size;
    const float* x  = (const float*)d_in[0];
    const float* qw = (const float*)d_in[1];
    const float* kw = (const float*)d_in[2];
    const float* vw = (const float*)d_in[3];
    const float* ow = (const float*)d_in[4];
    const float* ve = (const float*)d_in[5];
    const float* v0 = (const float*)d_in[6];
    const float* qg = (const float*)d_in[7];
    const float* vl = (const float*)d_in[8];
    const float* gw = (const float*)d_in[9];
    const float* gb = (const float*)d_in[10];

    float* out  = (float*)d_out;
    float* rawv = out + (size_t)BB*TT*DD;

    // workspace layout (float units)
    float* p    = (float*)d_ws;
    short* x16  = (short*)p;        p += 2097152;   // 4096*1024 bf16
    short* wb16 = (short*)p;        p += 786432;    // 1536*1024 bf16 (qw|kw|vw)
    short* ow16 = (short*)p;        p += 524288;    // 1024*1024 bf16
    short* qbh  = (short*)p;        p += 2097152;   // [b*16+h][t][d] bf16
    short* kbh  = (short*)p;        p += 524288;    // [b*4+kvh][t][d] bf16
    short* vtb  = (short*)p;        p += 524288;    // [b*4+kvh][d][t] bf16
    short* vb   = (short*)p;        p += 524288;    // [b][t][kvh][d] bf16 (pre-transpose)
    float* gt   = p;                p += 65536;     // 4096*16 f32
    short* y16  = (short*)p;                        // 4096*1024 bf16

    conv_all<<<6656, 256, 0, stream>>>(x, qw, kw, vw, ow, x16, wb16, ow16);
    // QKV projection + fused RMSNorm/RoPE/V-mix epilogue: M=4096, N=1536, K=1024
    gemm_qkv_fused<<<dim3(12, 32), 256, 0, stream>>>(x16, wb16, ve, v0, qg, vl,
                                                     qbh, kbh, vb, rawv);
    transpose_v<<<dim3(8, 32), 256, 0, stream>>>(vb, vtb);
    gate_kernel<<<4096, 256, 0, stream>>>(x16, gw, gb, gt);
    flash_mfma<<<dim3(32, 32), 256, 0, stream>>>(qbh, kbh, vtb, gt, y16);
    // out projection: M=4096, N=1024
    gemm_mfma<<<dim3(8, 32), 256, 0, stream>>>(y16, ow16, out, 1024, 1024);
}

// Round 3
// 186.109 us; speedup vs baseline: 1.1340x; 1.0736x over previous
//
#include <hip/hip_runtime.h>
#include <math.h>

#define BB 2
#define TT 2048
#define DD 1024
#define NH 16
#define NKV 4
#define HD 64
#define EPSF 1.1920929e-07f
// T=2048 > TSL=1024 -> nb = 10000 * 2^(64/62); log2(nb) = log2(1e4) + 64/62
#define LOG2_NB 14.319970444065578
// 0.125 (1/sqrt(64)) * log2(e): folded into q so softmax runs in exp2 domain
#define SCALE_LOG2E 0.18033688011112042f
// fixed softmax max (exp2 units): |q.k| <= 8*8*1.5*0.125*log2e = 17.31 < 17.5
#define FIXMAX 17.5f

typedef __attribute__((ext_vector_type(8))) short bf16x8;
typedef __attribute__((ext_vector_type(4))) float f32x4;

__device__ inline short f2bf(float f) {
    unsigned u = __builtin_bit_cast(unsigned, f);
    unsigned r = (u + 0x7fffu + ((u >> 16) & 1u)) >> 16;
    return (short)r;
}
__device__ inline float bf2f(short s) {
    unsigned u = ((unsigned)(unsigned short)s) << 16;
    return __builtin_bit_cast(float, u);
}
// packed f32x2 -> bf16x2 (hardware RNE rounding, 1 VALU op)
__device__ inline unsigned cvt_pk_bf16(float a, float b) {
    unsigned r;
    asm("v_cvt_pk_bf16_f32 %0, %1, %2" : "=v"(r) : "v"(a), "v"(b));
    return r;
}

// ---------------- fused fp32 -> bf16 conversion for all 6 tensors + gate-pad zero ----------------
// wb16 layout: rows 0-1023 qw | 1024-1279 kw | 1280-1535 vw | 1536-1551 gw | 1552-1663 zeros
__global__ __launch_bounds__(256) void conv_all(
    const float* __restrict__ x, const float* __restrict__ qw,
    const float* __restrict__ kw, const float* __restrict__ vw,
    const float* __restrict__ ow, const float* __restrict__ gw,
    short* __restrict__ x16, short* __restrict__ wb16, short* __restrict__ ow16)
{
    int i = blockIdx.x * 256 + threadIdx.x;   // float4 index
    if (i >= 1708032) {                        // zero-pad rows 1552-1663 of wb16
        ((short4*)(wb16 + 1552*1024))[i - 1708032] = (short4){0,0,0,0};
        return;
    }
    const float* src; short* dst; int j;
    if (i < 1048576)      { src = x;  dst = x16;            j = i; }
    else if (i < 1310720) { src = qw; dst = wb16;           j = i - 1048576; }
    else if (i < 1376256) { src = kw; dst = wb16 + 1048576; j = i - 1310720; }
    else if (i < 1441792) { src = vw; dst = wb16 + 1310720; j = i - 1376256; }
    else if (i < 1703936) { src = ow; dst = ow16;           j = i - 1441792; }
    else                  { src = gw; dst = wb16 + 1572864; j = i - 1703936; }
    float4 v = ((const float4*)src)[j];
    short4 o;
    o.x = f2bf(v.x); o.y = f2bf(v.y); o.z = f2bf(v.z); o.w = f2bf(v.w);
    ((short4*)dst)[j] = o;
}

// ---------------- shared staging macro for 128x128 bf16 GEMM tiles ----------------
#define GSTAGE(buf, k0, Abase, Bbase)                                                   \
{                                                                                       \
    _Pragma("unroll")                                                                   \
    for (int i_ = 0; i_ < 2; i_++) {                                                    \
        int off = w*2048 + i_*1024;           /* byte offset, wave-uniform */           \
        int g = (off >> 4) + lane;            /* 16B chunk idx */                       \
        int row = g >> 2, c = g & 3;                                                    \
        int cg = c ^ (row & 3);               /* XOR swizzle */                         \
        const short* ga = (Abase) + (size_t)(m0 + row)*1024 + (k0) + cg*8;              \
        __builtin_amdgcn_global_load_lds(                                               \
            (const __attribute__((address_space(1))) void*)ga,                          \
            (__attribute__((address_space(3))) void*)((char*)&As[buf][0] + off), 16, 0, 0); \
        const short* gb = (Bbase) + (size_t)(n0 + row)*1024 + (k0) + cg*8;              \
        __builtin_amdgcn_global_load_lds(                                               \
            (const __attribute__((address_space(1))) void*)gb,                          \
            (__attribute__((address_space(3))) void*)((char*)&Bs[buf][0] + off), 16, 0, 0); \
    }                                                                                   \
}

#define GEMM_MAIN_LOOP(kbeg, kend, Abase, Bbase)                                        \
    GSTAGE(0, (kbeg), (Abase), (Bbase));                                                \
    __syncthreads();                                                                    \
    for (int k0 = (kbeg); k0 < (kend); k0 += 32) {                                      \
        int cur = ((k0 - (kbeg)) >> 5) & 1;                                             \
        bf16x8 af[4], bfr[4];                                                           \
        _Pragma("unroll")                                                               \
        for (int tm = 0; tm < 4; tm++) {                                                \
            int row = wy*64 + tm*16 + lc;                                               \
            af[tm] = *(const bf16x8*)(&As[cur][0] + row*32 + ((quad*8) ^ ((row&3)*8))); \
        }                                                                               \
        _Pragma("unroll")                                                               \
        for (int tn = 0; tn < 4; tn++) {                                                \
            int row = wx*64 + tn*16 + lc;                                               \
            bfr[tn] = *(const bf16x8*)(&Bs[cur][0] + row*32 + ((quad*8) ^ ((row&3)*8))); \
        }                                                                               \
        if (k0 + 32 < (kend)) GSTAGE(cur ^ 1, k0 + 32, (Abase), (Bbase));               \
        _Pragma("unroll")                                                               \
        for (int tm = 0; tm < 4; tm++)                                                  \
            _Pragma("unroll")                                                           \
            for (int tn = 0; tn < 4; tn++)                                              \
                acc[tm][tn] = __builtin_amdgcn_mfma_f32_16x16x32_bf16(af[tm], bfr[tn], acc[tm][tn], 0, 0, 0); \
        __syncthreads();                                                                \
    }

// ---------------- QKV+gate GEMM with FUSED epilogue ----------------
// C = x16 * W^T (K=1024). N-cols: q 0-1023 | k 1024-1279 | v 1280-1535 | gate 1536-1551.
// q/k: RMSNorm + RoPE + gain*scale in-register -> bf16 qbh/kbh
// v:   +ve -> rawv (f32); lambda-mix -> bf16, in-block LDS transpose -> vtb [bk][d][t]
// gate: sigmoid(acc + gb) -> gate f32
__global__ __launch_bounds__(256, 3) void gemm_qkv_fused(
    const short* __restrict__ A, const short* __restrict__ Bmat,
    const float* __restrict__ ve, const float* __restrict__ v0,
    const float* __restrict__ q_gain, const float* __restrict__ vr_lambda,
    const float* __restrict__ gb_, float* __restrict__ gate,
    short* __restrict__ qbh, short* __restrict__ kbh, short* __restrict__ vtb,
    float* __restrict__ rawv)
{
    __shared__ short As[2][128*32];
    __shared__ short Bs[2][128*32];
    int tid = threadIdx.x;
    int w = tid >> 6, lane = tid & 63;
    int quad = lane >> 4, lc = lane & 15;
    int wy = w >> 1, wx = w & 1;
    int m0 = blockIdx.y * 128, n0 = blockIdx.x * 128;

    f32x4 acc[4][4];
    #pragma unroll
    for (int i = 0; i < 4; i++)
        #pragma unroll
        for (int j = 0; j < 4; j++) acc[i][j] = (f32x4){0.f,0.f,0.f,0.f};

    GEMM_MAIN_LOOP(0, 1024, A, Bmat);

    // ---- fused epilogue ----
    int hc = n0 + wx*64;                 // wave-uniform head column base
    if (hc < 1280) {
        // ---- q or k: RMSNorm over the head + RoPE (partner = tn^2, same lane) ----
        bool isq = (hc < 1024);
        int h = isq ? (hc >> 6) : ((hc - 1024) >> 6);
        float gsc = isq ? (q_gain[h] * SCALE_LOG2E) : 1.0f;
        short* dst = isq ? qbh : kbh;
        int nhh = isq ? 16 : 4;
        float inv0 = (float)exp2((double)lc * (-LOG2_NB / 32.0));
        float inv1 = (float)exp2((double)(lc + 16) * (-LOG2_NB / 32.0));
        #pragma unroll
        for (int tm = 0; tm < 4; tm++) {
            #pragma unroll
            for (int r = 0; r < 4; r++) {
                int m = m0 + wy*64 + tm*16 + quad*4 + r;
                int b = m >> 11, t = m & (TT - 1);
                float a0 = acc[tm][0][r], a1 = acc[tm][1][r];
                float a2 = acc[tm][2][r], a3 = acc[tm][3][r];
                float ss = a0*a0 + a1*a1 + a2*a2 + a3*a3;
                ss += __shfl_xor(ss, 1);
                ss += __shfl_xor(ss, 2);
                ss += __shfl_xor(ss, 4);
                ss += __shfl_xor(ss, 8);     // 16-lane quad holds one row
                float rn = rsqrtf(ss * (1.0f/64.0f) + EPSF);
                a0 *= rn; a1 *= rn; a2 *= rn; a3 *= rn;
                float sn0, cs0, sn1, cs1;
                sincosf((float)t * inv0, &sn0, &cs0);
                sincosf((float)t * inv1, &sn1, &cs1);
                float o0 = a0*cs0 + a2*sn0;      // d in [0,16)
                float o1 = a1*cs1 + a3*sn1;      // d in [16,32)
                float o2 = a2*cs0 - a0*sn0;      // d in [32,48)
                float o3 = a3*cs1 - a1*sn1;      // d in [48,64)
                size_t base = (((size_t)(b*nhh + h))*2048 + t)*64 + lc;
                dst[base +  0] = f2bf(o0 * gsc);
                dst[base + 16] = f2bf(o1 * gsc);
                dst[base + 32] = f2bf(o2 * gsc);
                dst[base + 48] = f2bf(o3 * gsc);
            }
        }
    } else if (hc < 1536) {
        // ---- v: +ve -> rawv ; lambda-mix -> LDS transpose -> vtb [bk][d][t] ----
        int kvh = (hc - 1280) >> 6;
        float l0 = vr_lambda[0], l1 = vr_lambda[1];
        // wave-private 8KB LDS region (As/Bs dead after main loop's final barrier)
        short* lbase = (w < 2) ? &As[w][0] : &Bs[w - 2][0];
        #pragma unroll
        for (int tm = 0; tm < 4; tm++) {
            #pragma unroll
            for (int r = 0; r < 4; r++) {
                int m = m0 + wy*64 + tm*16 + quad*4 + r;
                int tl = tm*16 + quad*4 + r;           // t-local within wave chunk
                size_t off = (size_t)m*256 + kvh*64 + lc;
                #pragma unroll
                for (int tn = 0; tn < 4; tn++) {
                    int d = tn*16 + lc;
                    float val = acc[tm][tn][r] + ve[off + tn*16];
                    rawv[off + tn*16] = val;
                    // store transposed [d][tl], XOR-swizzled to spread banks
                    lbase[d*64 + (tl ^ ((d & 7) * 8))] = f2bf(l0 * v0[off + tn*16] + l1 * val);
                }
            }
        }
        // wave-local: no barrier needed (own region, compiler orders LDS w->r)
        int b = m0 >> 11;
        int t0g = (m0 & 2047) + wy*64;
        short* vdst = vtb + (size_t)(b*4 + kvh)*64*2048;
        #pragma unroll
        for (int j = 0; j < 16; j++) {
            int d = quad + j*4;
            int tc = lc*4;
            // XOR mask touches bits 3-5 only; tc+0..3 stays contiguous
            short4 vv = *(const short4*)&lbase[d*64 + (tc ^ ((d & 7) * 8))];
            *(short4*)&vdst[(size_t)d*2048 + t0g + tc] = vv;
        }
    } else if (hc == 1536) {
        // ---- gate: sigmoid(acc[tm][0] + gb), heads = lc (cols 1536-1551) ----
        #pragma unroll
        for (int tm = 0; tm < 4; tm++)
            #pragma unroll
            for (int r = 0; r < 4; r++) {
                int m = m0 + wy*64 + tm*16 + quad*4 + r;
                float lg = acc[tm][0][r] + gb_[lc];
                gate[(size_t)m*16 + lc] = 1.0f / (1.0f + __expf(-lg));
            }
    }
    // hc == 1600: pad wave, nothing to store
}

// ---------------- generic bf16 MFMA GEMM: C = A * B^T (out projection) ----------------
__global__ __launch_bounds__(256, 4) void gemm_mfma(
    const short* __restrict__ A, const short* __restrict__ Bmat,
    float* __restrict__ C, int ldc, int klen)
{
    __shared__ short As[2][128*32];
    __shared__ short Bs[2][128*32];
    int tid = threadIdx.x;
    int w = tid >> 6, lane = tid & 63;
    int quad = lane >> 4, lc = lane & 15;
    int wy = w >> 1, wx = w & 1;
    int m0 = blockIdx.y * 128, n0 = blockIdx.x * 128;

    f32x4 acc[4][4];
    #pragma unroll
    for (int i = 0; i < 4; i++)
        #pragma unroll
        for (int j = 0; j < 4; j++) acc[i][j] = (f32x4){0.f,0.f,0.f,0.f};

    GEMM_MAIN_LOOP(0, klen, A, Bmat);

    #pragma unroll
    for (int tm = 0; tm < 4; tm++)
        #pragma unroll
        for (int r = 0; r < 4; r++) {
            int m = m0 + wy*64 + tm*16 + quad*4 + r;
            #pragma unroll
            for (int tn = 0; tn < 4; tn++) {
                int n = n0 + wx*64 + tn*16 + lc;
                C[(size_t)m*ldc + n] = acc[tm][tn][r];
            }
        }
}

// ---------------- MFMA flash attention v4: raw v_exp, packed bf16 cvt, l via ones-MFMA ----------------
__global__ __launch_bounds__(256, 4) void flash_mfma(
    const short* __restrict__ qbh, const short* __restrict__ kbh,
    const short* __restrict__ vtb, const float* __restrict__ gate,
    short* __restrict__ y16)
{
    __shared__ short Ks[2][64*64];
    __shared__ short Vt[2][64*64];
    __shared__ short Ps[4][16*64];   // per wave: row q=lc (16), 64 keys; 8B-chunk XOR swizzle

    int bh = blockIdx.x;             // b*16 + h
    int b = bh >> 4, h = bh & 15, kvh = h >> 2;
    int qt = 31 - blockIdx.y;        // long blocks launch first
    int tid = threadIdx.x;
    int w = tid >> 6, lane = tid & 63;
    int quad = lane >> 4, lc = lane & 15;

    const short* qbase = qbh + (((size_t)bh)*2048 + qt*64 + w*16 + lc)*64;
    bf16x8 qf0 = *(const bf16x8*)(qbase + quad*8);
    bf16x8 qf1 = *(const bf16x8*)(qbase + 32 + quad*8);

    f32x4 o[4];
    #pragma unroll
    for (int i = 0; i < 4; i++) o[i] = (f32x4){0.f,0.f,0.f,0.f};
    f32x4 l4 = (f32x4){0.f,0.f,0.f,0.f};      // l in C-layout via P x ones MFMA
    const bf16x8 ones = {(short)0x3F80,(short)0x3F80,(short)0x3F80,(short)0x3F80,
                         (short)0x3F80,(short)0x3F80,(short)0x3F80,(short)0x3F80};

    const size_t kbase = ((size_t)(b*4 + kvh))*2048*64;   // K [t][d]
    const size_t vbase = ((size_t)(b*4 + kvh))*64*2048;   // V^T [d][t]

    #define STAGE(buf, kt)                                                              \
    {                                                                                   \
        _Pragma("unroll")                                                               \
        for (int i = 0; i < 2; i++) {                                                   \
            int off = w*2048 + i*1024;                                                  \
            int g = (off >> 4) + lane;                                                  \
            int row = g >> 3, c = g & 7;                                                \
            int cg = c ^ (row & 7);                                                     \
            const short* gk = kbh + kbase + (size_t)((kt)*64 + row)*64 + cg*8;          \
            __builtin_amdgcn_global_load_lds(                                           \
                (const __attribute__((address_space(1))) void*)gk,                      \
                (__attribute__((address_space(3))) void*)((char*)Ks[buf] + off), 16, 0, 0); \
            const short* gv = vtb + vbase + (size_t)row*2048 + (kt)*64 + cg*8;          \
            __builtin_amdgcn_global_load_lds(                                           \
                (const __attribute__((address_space(1))) void*)gv,                      \
                (__attribute__((address_space(3))) void*)((char*)Vt[buf] + off), 16, 0, 0); \
        }                                                                               \
    }

    STAGE(0, 0);
    __syncthreads();

    short* ps = Ps[w];

    for (int kt = 0; kt <= qt; kt++) {
        int cur = kt & 1;
        bool diag = (kt == qt);

        // 1. preload ALL K/V fragments for this tile (no LDS reads after DMA issue)
        bf16x8 kf0[4], kf1[4], vf0[4], vf1[4];
        #pragma unroll
        for (int kn = 0; kn < 4; kn++) {
            int row = kn*16 + lc;
            int sw = (row & 7) * 8;
            const short* kr = Ks[cur] + row*64;
            kf0[kn] = *(const bf16x8*)(kr + ((quad*8) ^ sw));
            kf1[kn] = *(const bf16x8*)(kr + ((quad*8 + 32) ^ sw));
            const short* vr = Vt[cur] + row*64;
            vf0[kn] = *(const bf16x8*)(vr + ((quad*8) ^ sw));
            vf1[kn] = *(const bf16x8*)(vr + ((quad*8 + 32) ^ sw));
        }
        // 2. prefetch next K/V tile
        if (kt < qt) STAGE(cur ^ 1, kt + 1);

        // 3. S^T = K Q^T : lane holds cols q=lc, rows key = kn*16 + quad*4 + r
        f32x4 s4[4];
        #pragma unroll
        for (int kn = 0; kn < 4; kn++) {
            f32x4 acc = (f32x4){0.f,0.f,0.f,0.f};
            acc = __builtin_amdgcn_mfma_f32_16x16x32_bf16(kf0[kn], qf0, acc, 0, 0, 0);
            acc = __builtin_amdgcn_mfma_f32_16x16x32_bf16(kf1[kn], qf1, acc, 0, 0, 0);
            s4[kn] = acc;
        }

        // 4. p = exp2(s - FIXMAX) (raw v_exp_f32), causal mask, packed cvt, b64 P store
        #pragma unroll
        for (int kn = 0; kn < 4; kn++) {
            float p0 = __builtin_amdgcn_exp2f(s4[kn][0] - FIXMAX);
            float p1 = __builtin_amdgcn_exp2f(s4[kn][1] - FIXMAX);
            float p2 = __builtin_amdgcn_exp2f(s4[kn][2] - FIXMAX);
            float p3 = __builtin_amdgcn_exp2f(s4[kn][3] - FIXMAX);
            if (diag) {
                int keyb = kn*16 + quad*4, qv = w*16 + lc;
                if (keyb + 0 > qv) p0 = 0.f;
                if (keyb + 1 > qv) p1 = 0.f;
                if (keyb + 2 > qv) p2 = 0.f;
                if (keyb + 3 > qv) p3 = 0.f;
            }
            int c = kn*4 + quad;
            int cs = c ^ ((lc & 7) << 1);
            int2 pk;
            pk.x = (int)cvt_pk_bf16(p0, p1);
            pk.y = (int)cvt_pk_bf16(p2, p3);
            *(int2*)(ps + lc*64 + cs*4) = pk;
        }
        __asm__ volatile("s_waitcnt lgkmcnt(0)" ::: "memory");
        // P A-frags: row q=lc, keys kh*32 + quad*8 + (0..7)
        int u0 = (0*4 + quad) ^ (lc & 7);
        int u1 = (1*4 + quad) ^ (lc & 7);
        bf16x8 pf0 = *(const bf16x8*)(ps + lc*64 + u0*8);
        bf16x8 pf1 = *(const bf16x8*)(ps + lc*64 + u1*8);

        // 5. O += P V ; l4 += P x ones (l lands in C-layout rows quad*4+r)
        #pragma unroll
        for (int dn = 0; dn < 4; dn++) {
            o[dn] = __builtin_amdgcn_mfma_f32_16x16x32_bf16(pf0, vf0[dn], o[dn], 0, 0, 0);
            o[dn] = __builtin_amdgcn_mfma_f32_16x16x32_bf16(pf1, vf1[dn], o[dn], 0, 0, 0);
        }
        l4 = __builtin_amdgcn_mfma_f32_16x16x32_bf16(pf0, ones, l4, 0, 0, 0);
        l4 = __builtin_amdgcn_mfma_f32_16x16x32_bf16(pf1, ones, l4, 0, 0, 0);
        __syncthreads();
    }

    #pragma unroll
    for (int r = 0; r < 4; r++) {
        int row = b*2048 + qt*64 + w*16 + quad*4 + r;
        float g = gate[(size_t)row*16 + h] / l4[r];
        #pragma unroll
        for (int dn = 0; dn < 4; dn++)
            y16[(size_t)row*1024 + h*64 + dn*16 + lc] = f2bf(o[dn][r] * g);
    }
}

extern "C" void kernel_launch(void* const* d_in, const int* in_sizes, int n_in,
                              void* d_out, int out_size, void* d_ws, size_t ws_size,
                              hipStream_t stream) {
    (void)in_sizes; (void)n_in; (void)out_size; (void)ws_size;
    const float* x  = (const float*)d_in[0];
    const float* qw = (const float*)d_in[1];
    const float* kw = (const float*)d_in[2];
    const float* vw = (const float*)d_in[3];
    const float* ow = (const float*)d_in[4];
    const float* ve = (const float*)d_in[5];
    const float* v0 = (const float*)d_in[6];
    const float* qg = (const float*)d_in[7];
    const float* vl = (const float*)d_in[8];
    const float* gw = (const float*)d_in[9];
    const float* gb = (const float*)d_in[10];

    float* out  = (float*)d_out;
    float* rawv = out + (size_t)BB*TT*DD;

    // workspace layout (float units)
    float* p    = (float*)d_ws;
    short* x16  = (short*)p;        p += 2097152;   // 4096*1024 bf16
    short* wb16 = (short*)p;        p += 851968;    // 1664*1024 bf16 (qw|kw|vw|gw|zeros)
    short* ow16 = (short*)p;        p += 524288;    // 1024*1024 bf16
    short* qbh  = (short*)p;        p += 2097152;   // [b*16+h][t][d] bf16
    short* kbh  = (short*)p;        p += 524288;    // [b*4+kvh][t][d] bf16
    short* vtb  = (short*)p;        p += 524288;    // [b*4+kvh][d][t] bf16
    float* gt   = p;                p += 65536;     // 4096*16 f32
    short* y16  = (short*)p;                        // 4096*1024 bf16

    conv_all<<<6784, 256, 0, stream>>>(x, qw, kw, vw, ow, gw, x16, wb16, ow16);
    // QKV+gate projection + fused RMSNorm/RoPE/V-mix/V-transpose/gate epilogue
    // M=4096, N=1664 (13 col-blocks), K=1024
    gemm_qkv_fused<<<dim3(13, 32), 256, 0, stream>>>(x16, wb16, ve, v0, qg, vl,
                                                     gb, gt, qbh, kbh, vtb, rawv);
    flash_mfma<<<dim3(32, 32), 256, 0, stream>>>(qbh, kbh, vtb, gt, y16);
    // out projection: M=4096, N=1024
    gemm_mfma<<<dim3(8, 32), 256, 0, stream>>>(y16, ow16, out, 1024, 1024);
}

// Round 4
// 184.452 us; speedup vs baseline: 1.1442x; 1.0090x over previous
//
#include <hip/hip_runtime.h>
#include <math.h>

#define BB 2
#define TT 2048
#define DD 1024
#define NH 16
#define NKV 4
#define HD 64
#define EPSF 1.1920929e-07f
// T=2048 > TSL=1024 -> nb = 10000 * 2^(64/62); log2(nb) = log2(1e4) + 64/62
#define LOG2_NB 14.319970444065578
// 0.125 (1/sqrt(64)) * log2(e): folded into q so softmax runs in exp2 domain
#define SCALE_LOG2E 0.18033688011112042f
// fixed softmax max (exp2 units): |q.k| <= 8*8*1.5*0.125*log2e = 17.31 < 17.5
#define FIXMAX 17.5f

typedef __attribute__((ext_vector_type(8))) short bf16x8;
typedef __attribute__((ext_vector_type(4))) float f32x4;

__device__ inline short f2bf(float f) {
    unsigned u = __builtin_bit_cast(unsigned, f);
    unsigned r = (u + 0x7fffu + ((u >> 16) & 1u)) >> 16;
    return (short)r;
}
// packed f32x2 -> bf16x2 (hardware RNE rounding, 1 VALU op)
__device__ inline unsigned cvt_pk_bf16(float a, float b) {
    unsigned r;
    asm("v_cvt_pk_bf16_f32 %0, %1, %2" : "=v"(r) : "v"(a), "v"(b));
    return r;
}

// ---------------- shared staging macro for 128x128 bf16 GEMM tiles (bf16 src) ----------------
#define GSTAGE(buf, k0, Abase, Bbase)                                                   \
{                                                                                       \
    _Pragma("unroll")                                                                   \
    for (int i_ = 0; i_ < 2; i_++) {                                                    \
        int off = w*2048 + i_*1024;           /* byte offset, wave-uniform */           \
        int g = (off >> 4) + lane;            /* 16B chunk idx */                       \
        int row = g >> 2, c = g & 3;                                                    \
        int cg = c ^ (row & 3);               /* XOR swizzle */                         \
        const short* ga = (Abase) + (size_t)(m0 + row)*1024 + (k0) + cg*8;              \
        __builtin_amdgcn_global_load_lds(                                               \
            (const __attribute__((address_space(1))) void*)ga,                          \
            (__attribute__((address_space(3))) void*)((char*)&As[buf][0] + off), 16, 0, 0); \
        const short* gb = (Bbase) + (size_t)(n0 + row)*1024 + (k0) + cg*8;              \
        __builtin_amdgcn_global_load_lds(                                               \
            (const __attribute__((address_space(1))) void*)gb,                          \
            (__attribute__((address_space(3))) void*)((char*)&Bs[buf][0] + off), 16, 0, 0); \
    }                                                                                   \
}

#define GEMM_MAIN_LOOP(kbeg, kend, Abase, Bbase)                                        \
    GSTAGE(0, (kbeg), (Abase), (Bbase));                                                \
    __syncthreads();                                                                    \
    for (int k0 = (kbeg); k0 < (kend); k0 += 32) {                                      \
        int cur = ((k0 - (kbeg)) >> 5) & 1;                                             \
        bf16x8 af[4], bfr[4];                                                           \
        _Pragma("unroll")                                                               \
        for (int tm = 0; tm < 4; tm++) {                                                \
            int row = wy*64 + tm*16 + lc;                                               \
            af[tm] = *(const bf16x8*)(&As[cur][0] + row*32 + ((quad*8) ^ ((row&3)*8))); \
        }                                                                               \
        _Pragma("unroll")                                                               \
        for (int tn = 0; tn < 4; tn++) {                                                \
            int row = wx*64 + tn*16 + lc;                                               \
            bfr[tn] = *(const bf16x8*)(&Bs[cur][0] + row*32 + ((quad*8) ^ ((row&3)*8))); \
        }                                                                               \
        if (k0 + 32 < (kend)) GSTAGE(cur ^ 1, k0 + 32, (Abase), (Bbase));               \
        _Pragma("unroll")                                                               \
        for (int tm = 0; tm < 4; tm++)                                                  \
            _Pragma("unroll")                                                           \
            for (int tn = 0; tn < 4; tn++)                                              \
                acc[tm][tn] = __builtin_amdgcn_mfma_f32_16x16x32_bf16(af[tm], bfr[tn], acc[tm][tn], 0, 0, 0); \
        __syncthreads();                                                                \
    }

// ---------------- QKV+gate GEMM, f32 inputs with on-the-fly bf16 conversion ----------------
// C = x * W^T (K=1024). N-cols: q 0-1023 | k 1024-1279 | v 1280-1535 | gate 1536-1551 | pad.
// Staging: reg-stage f32 -> cvt_pk_bf16 -> ds_write (T14 split: loads issued before MFMA,
// cvt+write after). LDS image identical to the global_load_lds layout.
// Epilogue: q/k RMSNorm+RoPE+gain -> qbh/kbh; v +ve->rawv, mix+LDS-transpose -> vtb;
// gate sigmoid -> gt; plus grid-strided ow f32->bf16 conversion tail.
__global__ __launch_bounds__(256, 2) void gemm_qkv_fused(
    const float* __restrict__ x, const float* __restrict__ qw,
    const float* __restrict__ kw, const float* __restrict__ vw,
    const float* __restrict__ gw, const float* __restrict__ ow,
    const float* __restrict__ ve, const float* __restrict__ v0,
    const float* __restrict__ q_gain, const float* __restrict__ vr_lambda,
    const float* __restrict__ gb_, float* __restrict__ gate,
    short* __restrict__ qbh, short* __restrict__ kbh, short* __restrict__ vtb,
    float* __restrict__ rawv, short* __restrict__ ow16)
{
    __shared__ short As[2][128*32];
    __shared__ short Bs[2][128*32];
    int tid = threadIdx.x;
    int w = tid >> 6, lane = tid & 63;
    int quad = lane >> 4, lc = lane & 15;
    int wy = w >> 1, wx = w & 1;
    int m0 = blockIdx.y * 128, n0 = blockIdx.x * 128;

    // ---- per-thread staging geometry (fixed across K-steps) ----
    int g0 = w*128 + lane;            // chunk slot 0
    int g1 = w*128 + 64 + lane;       // chunk slot 1
    int rA0 = g0 >> 2, rA1 = g1 >> 2;
    int cg0 = (g0 & 3) ^ (rA0 & 3);   // XOR-swizzled col-group
    int cg1 = (g1 & 3) ^ (rA1 & 3);
    const float* aptr0 = x + (size_t)(m0 + rA0)*1024 + cg0*8;
    const float* aptr1 = x + (size_t)(m0 + rA1)*1024 + cg1*8;
    // B row -> source matrix select (rows >=1552 are zero-masked, safe-clamped to gw)
    int nB0 = n0 + rA0, nB1 = n0 + rA1;
    const float* bptr0;
    if      (nB0 < 1024) bptr0 = qw + (size_t)nB0*1024;
    else if (nB0 < 1280) bptr0 = kw + (size_t)(nB0-1024)*1024;
    else if (nB0 < 1536) bptr0 = vw + (size_t)(nB0-1280)*1024;
    else                 bptr0 = gw + (size_t)((nB0-1536)&15)*1024;
    const float* bptr1;
    if      (nB1 < 1024) bptr1 = qw + (size_t)nB1*1024;
    else if (nB1 < 1280) bptr1 = kw + (size_t)(nB1-1024)*1024;
    else if (nB1 < 1536) bptr1 = vw + (size_t)(nB1-1280)*1024;
    else                 bptr1 = gw + (size_t)((nB1-1536)&15)*1024;
    bptr0 += cg0*8; bptr1 += cg1*8;
    unsigned bmask0 = (nB0 < 1552) ? 0xFFFFFFFFu : 0u;
    unsigned bmask1 = (nB1 < 1552) ? 0xFFFFFFFFu : 0u;

    float4 A0a, A0b, A1a, A1b, B0a, B0b, B1a, B1b;

    #define QSTG_LOAD(k0)                                                   \
    {                                                                       \
        A0a = *(const float4*)(aptr0 + (k0));                               \
        A0b = *(const float4*)(aptr0 + (k0) + 4);                           \
        A1a = *(const float4*)(aptr1 + (k0));                               \
        A1b = *(const float4*)(aptr1 + (k0) + 4);                           \
        B0a = *(const float4*)(bptr0 + (k0));                               \
        B0b = *(const float4*)(bptr0 + (k0) + 4);                           \
        B1a = *(const float4*)(bptr1 + (k0));                               \
        B1b = *(const float4*)(bptr1 + (k0) + 4);                           \
    }

    #define QSTG_WRITE(buf)                                                 \
    {                                                                       \
        unsigned q0, q1, q2, q3; int4 pk;                                   \
        q0 = cvt_pk_bf16(A0a.x, A0a.y); q1 = cvt_pk_bf16(A0a.z, A0a.w);     \
        q2 = cvt_pk_bf16(A0b.x, A0b.y); q3 = cvt_pk_bf16(A0b.z, A0b.w);     \
        pk = (int4){(int)q0,(int)q1,(int)q2,(int)q3};                       \
        *(int4*)((char*)&As[buf][0] + w*2048 + lane*16) = pk;               \
        q0 = cvt_pk_bf16(A1a.x, A1a.y); q1 = cvt_pk_bf16(A1a.z, A1a.w);     \
        q2 = cvt_pk_bf16(A1b.x, A1b.y); q3 = cvt_pk_bf16(A1b.z, A1b.w);     \
        pk = (int4){(int)q0,(int)q1,(int)q2,(int)q3};                       \
        *(int4*)((char*)&As[buf][0] + w*2048 + 1024 + lane*16) = pk;        \
        q0 = cvt_pk_bf16(B0a.x, B0a.y) & bmask0;                            \
        q1 = cvt_pk_bf16(B0a.z, B0a.w) & bmask0;                            \
        q2 = cvt_pk_bf16(B0b.x, B0b.y) & bmask0;                            \
        q3 = cvt_pk_bf16(B0b.z, B0b.w) & bmask0;                            \
        pk = (int4){(int)q0,(int)q1,(int)q2,(int)q3};                       \
        *(int4*)((char*)&Bs[buf][0] + w*2048 + lane*16) = pk;               \
        q0 = cvt_pk_bf16(B1a.x, B1a.y) & bmask1;                            \
        q1 = cvt_pk_bf16(B1a.z, B1a.w) & bmask1;                            \
        q2 = cvt_pk_bf16(B1b.x, B1b.y) & bmask1;                            \
        q3 = cvt_pk_bf16(B1b.z, B1b.w) & bmask1;                            \
        pk = (int4){(int)q0,(int)q1,(int)q2,(int)q3};                       \
        *(int4*)((char*)&Bs[buf][0] + w*2048 + 1024 + lane*16) = pk;        \
    }

    f32x4 acc[4][4];
    #pragma unroll
    for (int i = 0; i < 4; i++)
        #pragma unroll
        for (int j = 0; j < 4; j++) acc[i][j] = (f32x4){0.f,0.f,0.f,0.f};

    QSTG_LOAD(0);
    QSTG_WRITE(0);
    __syncthreads();

    for (int k0 = 0; k0 < 1024; k0 += 32) {
        int cur = (k0 >> 5) & 1;
        bool pre = (k0 + 32) < 1024;
        bf16x8 af[4], bfr[4];
        #pragma unroll
        for (int tm = 0; tm < 4; tm++) {
            int row = wy*64 + tm*16 + lc;
            af[tm] = *(const bf16x8*)(&As[cur][0] + row*32 + ((quad*8) ^ ((row&3)*8)));
        }
        #pragma unroll
        for (int tn = 0; tn < 4; tn++) {
            int row = wx*64 + tn*16 + lc;
            bfr[tn] = *(const bf16x8*)(&Bs[cur][0] + row*32 + ((quad*8) ^ ((row&3)*8)));
        }
        // issue next-slice loads before compute; latency hides under MFMA
        if (pre) QSTG_LOAD(k0 + 32);
        #pragma unroll
        for (int tm = 0; tm < 4; tm++)
            #pragma unroll
            for (int tn = 0; tn < 4; tn++)
                acc[tm][tn] = __builtin_amdgcn_mfma_f32_16x16x32_bf16(af[tm], bfr[tn], acc[tm][tn], 0, 0, 0);
        // vmcnt-wait lands here; convert + write the other buffer
        if (pre) QSTG_WRITE(cur ^ 1);
        __syncthreads();
    }

    // ---- fused epilogue ----
    int hc = n0 + wx*64;                 // wave-uniform head column base
    if (hc < 1280) {
        // ---- q or k: RMSNorm over the head + RoPE (partner = tn^2, same lane) ----
        bool isq = (hc < 1024);
        int h = isq ? (hc >> 6) : ((hc - 1024) >> 6);
        float gsc = isq ? (q_gain[h] * SCALE_LOG2E) : 1.0f;
        short* dst = isq ? qbh : kbh;
        int nhh = isq ? 16 : 4;
        float inv0 = (float)exp2((double)lc * (-LOG2_NB / 32.0));
        float inv1 = (float)exp2((double)(lc + 16) * (-LOG2_NB / 32.0));
        #pragma unroll
        for (int tm = 0; tm < 4; tm++) {
            #pragma unroll
            for (int r = 0; r < 4; r++) {
                int m = m0 + wy*64 + tm*16 + quad*4 + r;
                int b = m >> 11, t = m & (TT - 1);
                float a0 = acc[tm][0][r], a1 = acc[tm][1][r];
                float a2 = acc[tm][2][r], a3 = acc[tm][3][r];
                float ss = a0*a0 + a1*a1 + a2*a2 + a3*a3;
                ss += __shfl_xor(ss, 1);
                ss += __shfl_xor(ss, 2);
                ss += __shfl_xor(ss, 4);
                ss += __shfl_xor(ss, 8);     // 16-lane quad holds one row
                float rn = rsqrtf(ss * (1.0f/64.0f) + EPSF);
                a0 *= rn; a1 *= rn; a2 *= rn; a3 *= rn;
                float sn0, cs0, sn1, cs1;
                sincosf((float)t * inv0, &sn0, &cs0);
                sincosf((float)t * inv1, &sn1, &cs1);
                float o0 = a0*cs0 + a2*sn0;      // d in [0,16)
                float o1 = a1*cs1 + a3*sn1;      // d in [16,32)
                float o2 = a2*cs0 - a0*sn0;      // d in [32,48)
                float o3 = a3*cs1 - a1*sn1;      // d in [48,64)
                size_t base = (((size_t)(b*nhh + h))*2048 + t)*64 + lc;
                dst[base +  0] = f2bf(o0 * gsc);
                dst[base + 16] = f2bf(o1 * gsc);
                dst[base + 32] = f2bf(o2 * gsc);
                dst[base + 48] = f2bf(o3 * gsc);
            }
        }
    } else if (hc < 1536) {
        // ---- v: +ve -> rawv ; lambda-mix -> LDS transpose -> vtb [bk][d][t] ----
        int kvh = (hc - 1280) >> 6;
        float l0 = vr_lambda[0], l1 = vr_lambda[1];
        // wave-private 8KB LDS region (As/Bs dead after main loop's final barrier)
        short* lbase = (w < 2) ? &As[w][0] : &Bs[w - 2][0];
        #pragma unroll
        for (int tm = 0; tm < 4; tm++) {
            #pragma unroll
            for (int r = 0; r < 4; r++) {
                int m = m0 + wy*64 + tm*16 + quad*4 + r;
                int tl = tm*16 + quad*4 + r;           // t-local within wave chunk
                size_t off = (size_t)m*256 + kvh*64 + lc;
                #pragma unroll
                for (int tn = 0; tn < 4; tn++) {
                    int d = tn*16 + lc;
                    float val = acc[tm][tn][r] + ve[off + tn*16];
                    rawv[off + tn*16] = val;
                    // store transposed [d][tl], XOR-swizzled to spread banks
                    lbase[d*64 + (tl ^ ((d & 7) * 8))] = f2bf(l0 * v0[off + tn*16] + l1 * val);
                }
            }
        }
        // wave-local: no barrier needed (own region, compiler orders LDS w->r)
        int b = m0 >> 11;
        int t0g = (m0 & 2047) + wy*64;
        short* vdst = vtb + (size_t)(b*4 + kvh)*64*2048;
        #pragma unroll
        for (int j = 0; j < 16; j++) {
            int d = quad + j*4;
            int tc = lc*4;
            // XOR mask touches bits 3-5 only; tc+0..3 stays contiguous
            short4 vv = *(const short4*)&lbase[d*64 + (tc ^ ((d & 7) * 8))];
            *(short4*)&vdst[(size_t)d*2048 + t0g + tc] = vv;
        }
    } else if (hc == 1536) {
        // ---- gate: sigmoid(acc[tm][0] + gb), heads = lc (cols 1536-1551) ----
        #pragma unroll
        for (int tm = 0; tm < 4; tm++)
            #pragma unroll
            for (int r = 0; r < 4; r++) {
                int m = m0 + wy*64 + tm*16 + quad*4 + r;
                float lg = acc[tm][0][r] + gb_[lc];
                gate[(size_t)m*16 + lc] = 1.0f / (1.0f + __expf(-lg));
            }
    }
    // hc == 1600: pad wave, nothing to store

    // ---- ow f32 -> bf16 conversion tail (grid-strided over all 416 blocks) ----
    int gtid = (blockIdx.y * 13 + blockIdx.x) * 256 + tid;   // 0..106495
    for (int idx = gtid; idx < 262144; idx += 106496) {
        float4 v = ((const float4*)ow)[idx];
        short4 o;
        o.x = f2bf(v.x); o.y = f2bf(v.y); o.z = f2bf(v.z); o.w = f2bf(v.w);
        ((short4*)ow16)[idx] = o;
    }
    #undef QSTG_LOAD
    #undef QSTG_WRITE
}

// ---------------- generic bf16 MFMA GEMM: C = A * B^T (out projection) ----------------
__global__ __launch_bounds__(256, 4) void gemm_mfma(
    const short* __restrict__ A, const short* __restrict__ Bmat,
    float* __restrict__ C, int ldc, int klen)
{
    __shared__ short As[2][128*32];
    __shared__ short Bs[2][128*32];
    int tid = threadIdx.x;
    int w = tid >> 6, lane = tid & 63;
    int quad = lane >> 4, lc = lane & 15;
    int wy = w >> 1, wx = w & 1;
    int m0 = blockIdx.y * 128, n0 = blockIdx.x * 128;

    f32x4 acc[4][4];
    #pragma unroll
    for (int i = 0; i < 4; i++)
        #pragma unroll
        for (int j = 0; j < 4; j++) acc[i][j] = (f32x4){0.f,0.f,0.f,0.f};

    GEMM_MAIN_LOOP(0, klen, A, Bmat);

    #pragma unroll
    for (int tm = 0; tm < 4; tm++)
        #pragma unroll
        for (int r = 0; r < 4; r++) {
            int m = m0 + wy*64 + tm*16 + quad*4 + r;
            #pragma unroll
            for (int tn = 0; tn < 4; tn++) {
                int n = n0 + wx*64 + tn*16 + lc;
                C[(size_t)m*ldc + n] = acc[tm][tn][r];
            }
        }
}

// ---------------- MFMA flash attention v4: raw v_exp, packed bf16 cvt, l via ones-MFMA ----------------
__global__ __launch_bounds__(256, 4) void flash_mfma(
    const short* __restrict__ qbh, const short* __restrict__ kbh,
    const short* __restrict__ vtb, const float* __restrict__ gate,
    short* __restrict__ y16)
{
    __shared__ short Ks[2][64*64];
    __shared__ short Vt[2][64*64];
    __shared__ short Ps[4][16*64];   // per wave: row q=lc (16), 64 keys; 8B-chunk XOR swizzle

    int bh = blockIdx.x;             // b*16 + h
    int b = bh >> 4, h = bh & 15, kvh = h >> 2;
    int qt = 31 - blockIdx.y;        // long blocks launch first
    int tid = threadIdx.x;
    int w = tid >> 6, lane = tid & 63;
    int quad = lane >> 4, lc = lane & 15;

    const short* qbase = qbh + (((size_t)bh)*2048 + qt*64 + w*16 + lc)*64;
    bf16x8 qf0 = *(const bf16x8*)(qbase + quad*8);
    bf16x8 qf1 = *(const bf16x8*)(qbase + 32 + quad*8);

    f32x4 o[4];
    #pragma unroll
    for (int i = 0; i < 4; i++) o[i] = (f32x4){0.f,0.f,0.f,0.f};
    f32x4 l4 = (f32x4){0.f,0.f,0.f,0.f};      // l in C-layout via P x ones MFMA
    const bf16x8 ones = {(short)0x3F80,(short)0x3F80,(short)0x3F80,(short)0x3F80,
                         (short)0x3F80,(short)0x3F80,(short)0x3F80,(short)0x3F80};

    const size_t kbase = ((size_t)(b*4 + kvh))*2048*64;   // K [t][d]
    const size_t vbase = ((size_t)(b*4 + kvh))*64*2048;   // V^T [d][t]

    #define STAGE(buf, kt)                                                              \
    {                                                                                   \
        _Pragma("unroll")                                                               \
        for (int i = 0; i < 2; i++) {                                                   \
            int off = w*2048 + i*1024;                                                  \
            int g = (off >> 4) + lane;                                                  \
            int row = g >> 3, c = g & 7;                                                \
            int cg = c ^ (row & 7);                                                     \
            const short* gk = kbh + kbase + (size_t)((kt)*64 + row)*64 + cg*8;          \
            __builtin_amdgcn_global_load_lds(                                           \
                (const __attribute__((address_space(1))) void*)gk,                      \
                (__attribute__((address_space(3))) void*)((char*)Ks[buf] + off), 16, 0, 0); \
            const short* gv = vtb + vbase + (size_t)row*2048 + (kt)*64 + cg*8;          \
            __builtin_amdgcn_global_load_lds(                                           \
                (const __attribute__((address_space(1))) void*)gv,                      \
                (__attribute__((address_space(3))) void*)((char*)Vt[buf] + off), 16, 0, 0); \
        }                                                                               \
    }

    STAGE(0, 0);
    __syncthreads();

    short* ps = Ps[w];

    for (int kt = 0; kt <= qt; kt++) {
        int cur = kt & 1;
        bool diag = (kt == qt);

        // 1. preload ALL K/V fragments for this tile (no LDS reads after DMA issue)
        bf16x8 kf0[4], kf1[4], vf0[4], vf1[4];
        #pragma unroll
        for (int kn = 0; kn < 4; kn++) {
            int row = kn*16 + lc;
            int sw = (row & 7) * 8;
            const short* kr = Ks[cur] + row*64;
            kf0[kn] = *(const bf16x8*)(kr + ((quad*8) ^ sw));
            kf1[kn] = *(const bf16x8*)(kr + ((quad*8 + 32) ^ sw));
            const short* vr = Vt[cur] + row*64;
            vf0[kn] = *(const bf16x8*)(vr + ((quad*8) ^ sw));
            vf1[kn] = *(const bf16x8*)(vr + ((quad*8 + 32) ^ sw));
        }
        // 2. prefetch next K/V tile
        if (kt < qt) STAGE(cur ^ 1, kt + 1);

        // 3. S^T = K Q^T : lane holds cols q=lc, rows key = kn*16 + quad*4 + r
        f32x4 s4[4];
        #pragma unroll
        for (int kn = 0; kn < 4; kn++) {
            f32x4 acc = (f32x4){0.f,0.f,0.f,0.f};
            acc = __builtin_amdgcn_mfma_f32_16x16x32_bf16(kf0[kn], qf0, acc, 0, 0, 0);
            acc = __builtin_amdgcn_mfma_f32_16x16x32_bf16(kf1[kn], qf1, acc, 0, 0, 0);
            s4[kn] = acc;
        }

        // 4. p = exp2(s - FIXMAX) (raw v_exp_f32), causal mask, packed cvt, b64 P store
        #pragma unroll
        for (int kn = 0; kn < 4; kn++) {
            float p0 = __builtin_amdgcn_exp2f(s4[kn][0] - FIXMAX);
            float p1 = __builtin_amdgcn_exp2f(s4[kn][1] - FIXMAX);
            float p2 = __builtin_amdgcn_exp2f(s4[kn][2] - FIXMAX);
            float p3 = __builtin_amdgcn_exp2f(s4[kn][3] - FIXMAX);
            if (diag) {
                int keyb = kn*16 + quad*4, qv = w*16 + lc;
                if (keyb + 0 > qv) p0 = 0.f;
                if (keyb + 1 > qv) p1 = 0.f;
                if (keyb + 2 > qv) p2 = 0.f;
                if (keyb + 3 > qv) p3 = 0.f;
            }
            int c = kn*4 + quad;
            int cs = c ^ ((lc & 7) << 1);
            int2 pk;
            pk.x = (int)cvt_pk_bf16(p0, p1);
            pk.y = (int)cvt_pk_bf16(p2, p3);
            *(int2*)(ps + lc*64 + cs*4) = pk;
        }
        __asm__ volatile("s_waitcnt lgkmcnt(0)" ::: "memory");
        // P A-frags: row q=lc, keys kh*32 + quad*8 + (0..7)
        int u0 = (0*4 + quad) ^ (lc & 7);
        int u1 = (1*4 + quad) ^ (lc & 7);
        bf16x8 pf0 = *(const bf16x8*)(ps + lc*64 + u0*8);
        bf16x8 pf1 = *(const bf16x8*)(ps + lc*64 + u1*8);

        // 5. O += P V ; l4 += P x ones (l lands in C-layout rows quad*4+r)
        #pragma unroll
        for (int dn = 0; dn < 4; dn++) {
            o[dn] = __builtin_amdgcn_mfma_f32_16x16x32_bf16(pf0, vf0[dn], o[dn], 0, 0, 0);
            o[dn] = __builtin_amdgcn_mfma_f32_16x16x32_bf16(pf1, vf1[dn], o[dn], 0, 0, 0);
        }
        l4 = __builtin_amdgcn_mfma_f32_16x16x32_bf16(pf0, ones, l4, 0, 0, 0);
        l4 = __builtin_amdgcn_mfma_f32_16x16x32_bf16(pf1, ones, l4, 0, 0, 0);
        __syncthreads();
    }

    #pragma unroll
    for (int r = 0; r < 4; r++) {
        int row = b*2048 + qt*64 + w*16 + quad*4 + r;
        float g = gate[(size_t)row*16 + h] / l4[r];
        #pragma unroll
        for (int dn = 0; dn < 4; dn++)
            y16[(size_t)row*1024 + h*64 + dn*16 + lc] = f2bf(o[dn][r] * g);
    }
}

extern "C" void kernel_launch(void* const* d_in, const int* in_sizes, int n_in,
                              void* d_out, int out_size, void* d_ws, size_t ws_size,
                              hipStream_t stream) {
    (void)in_sizes; (void)n_in; (void)out_size; (void)ws_size;
    const float* x  = (const float*)d_in[0];
    const float* qw = (const float*)d_in[1];
    const float* kw = (const float*)d_in[2];
    const float* vw = (const float*)d_in[3];
    const float* ow = (const float*)d_in[4];
    const float* ve = (const float*)d_in[5];
    const float* v0 = (const float*)d_in[6];
    const float* qg = (const float*)d_in[7];
    const float* vl = (const float*)d_in[8];
    const float* gw = (const float*)d_in[9];
    const float* gb = (const float*)d_in[10];

    float* out  = (float*)d_out;
    float* rawv = out + (size_t)BB*TT*DD;

    // workspace layout (float units)
    float* p    = (float*)d_ws;
    short* ow16 = (short*)p;        p += 524288;    // 1024*1024 bf16
    short* qbh  = (short*)p;        p += 2097152;   // [b*16+h][t][d] bf16
    short* kbh  = (short*)p;        p += 524288;    // [b*4+kvh][t][d] bf16
    short* vtb  = (short*)p;        p += 524288;    // [b*4+kvh][d][t] bf16
    float* gt   = p;                p += 65536;     // 4096*16 f32
    short* y16  = (short*)p;                        // 4096*1024 bf16

    // QKV+gate projection from f32 inputs (on-the-fly bf16), fused epilogue + ow conversion
    // M=4096, N=1664 (13 col-blocks), K=1024
    gemm_qkv_fused<<<dim3(13, 32), 256, 0, stream>>>(x, qw, kw, vw, gw, ow,
                                                     ve, v0, qg, vl, gb, gt,
                                                     qbh, kbh, vtb, rawv, ow16);
    flash_mfma<<<dim3(32, 32), 256, 0, stream>>>(qbh, kbh, vtb, gt, y16);
    // out projection: M=4096, N=1024
    gemm_mfma<<<dim3(8, 32), 256, 0, stream>>>(y16, ow16, out, 1024, 1024);
}